// Round 1
// baseline (271.928 us; speedup 1.0000x reference)
//
#include <hip/hip_runtime.h>
#include <stdint.h>

#define BI 128
#define BT 128
#define KIMG 36
#define LCAP 64
#define DD 1024
#define MP 48   // imgs K padded to 3x16 for MFMA alignment

typedef _Float16 h4 __attribute__((ext_vector_type(4)));
typedef _Float16 h8 __attribute__((ext_vector_type(8)));
typedef float f4 __attribute__((ext_vector_type(4)));

__device__ __forceinline__ float wave_red_sum(float v) {
#pragma unroll
  for (int o = 1; o < 64; o <<= 1) v += __shfl_xor(v, o, 64);
  return v;
}
__device__ __forceinline__ float wave_red_max(float v) {
#pragma unroll
  for (int o = 1; o < 64; o <<= 1) v = fmaxf(v, __shfl_xor(v, o, 64));
  return v;
}

// ---------------------------------------------------------------------------
// Kernel 1: add EPS, L2-normalize rows over D=1024, cast to fp16.
// imgs rows are written into a padded [BI][MP=48][DD] layout (rows 36..47 = 0).
// One 256-thread block per row; each thread owns 4 consecutive floats.
// ---------------------------------------------------------------------------
__global__ __launch_bounds__(256) void norm_kernel(
    const float* __restrict__ imgs, const float* __restrict__ caps,
    _Float16* __restrict__ Ah, _Float16* __restrict__ Bh) {
  int row = blockIdx.x;
  int tid = threadIdx.x;
  const float* src;
  _Float16* dst;
  if (row < BI * MP) {
    int i = row / MP, k = row - i * MP;
    dst = Ah + (size_t)row * DD;
    if (k >= KIMG) {           // zero padding rows (block-uniform branch)
      h4 z = {};
      ((h4*)dst)[tid] = z;
      return;
    }
    src = imgs + ((size_t)i * KIMG + k) * DD;
  } else {
    int r = row - BI * MP;
    dst = Bh + (size_t)r * DD;
    src = caps + (size_t)r * DD;
  }
  float4 x = ((const float4*)src)[tid];
  x.x += 1e-6f; x.y += 1e-6f; x.z += 1e-6f; x.w += 1e-6f;
  float ss = x.x * x.x + x.y * x.y + x.z * x.z + x.w * x.w;
  ss = wave_red_sum(ss);
  __shared__ float red[4];
  int lane = tid & 63, w = tid >> 6;
  if (lane == 0) red[w] = ss;
  __syncthreads();
  float scale = rsqrtf(red[0] + red[1] + red[2] + red[3]);
  h4 o;
  o[0] = (_Float16)(x.x * scale);
  o[1] = (_Float16)(x.y * scale);
  o[2] = (_Float16)(x.z * scale);
  o[3] = (_Float16)(x.w * scale);
  ((h4*)dst)[tid] = o;
}

// ---------------------------------------------------------------------------
// Kernel 2: fused GEMM (one image x two captions -> 48x128 fp16-MFMA tile)
// + masked dual-axis softmax + reductions -> sims[i, t0], sims[i, t1].
// Block: 256 threads (4 waves). Wave w owns columns [32w, 32w+32).
// ---------------------------------------------------------------------------
__global__ __launch_bounds__(256) void sims_kernel(
    const _Float16* __restrict__ Ah, const _Float16* __restrict__ Bh,
    const int* __restrict__ img_lens, const int* __restrict__ cap_lens,
    float* __restrict__ out) {
  // staging: As 48x32 fp16 (3 KB) followed by Bs 128x32 fp16 (8 KB), linear
  __shared__ _Float16 stage[5632] __attribute__((aligned(16)));
  __shared__ float S[MP][129];            // +1 pad column group vs bank stride
  __shared__ float colred[2][2][2][64];   // [e|es][t][rowgroup][col]
  __shared__ float mred[2][2];
  __shared__ float vred[2][2];

  int tid = threadIdx.x;
  int lane = tid & 63;
  int w = tid >> 6;
  int bx = blockIdx.x;    // caption pair index 0..63
  int iblk = blockIdx.y;  // image index 0..127

  f4 acc[3][2] = {};
  int fr = lane & 15;     // fragment row (M or N index)
  int fq = lane >> 4;     // k-segment 0..3 (8 halves each)

  const size_t arow0 = (size_t)iblk * MP;
  const size_t brow0 = (size_t)bx * 128;

  for (int k0 = 0; k0 < DD; k0 += 32) {
    // ---- stage 11 KB = 11 wave-chunks of 1 KB via global_load_lds(16B) ----
#pragma unroll
    for (int it = 0; it < 3; ++it) {
      int c = w + 4 * it;
      if (c < 11) {
        int X = c * 1024 + lane * 16;   // byte offset in staging buffer
        const _Float16* g;
        if (X < 3072) {                 // As region (wave-uniform branch)
          int row = X >> 6;             // 64 B per 32-half row
          int b = X & 63;
          g = Ah + (arow0 + row) * DD + k0 + (b >> 1);
        } else {                        // Bs region
          int Y = X - 3072;
          int row = Y >> 6;
          int b = Y & 63;
          g = Bh + (brow0 + row) * DD + k0 + (b >> 1);
        }
        __builtin_amdgcn_global_load_lds(
            (const __attribute__((address_space(1))) void*)g,
            (__attribute__((address_space(3))) void*)((char*)stage + c * 1024),
            16, 0, 0);
      }
    }
    __syncthreads();
    // ---- compute: 3 A-frags x 2 B-frags -> 6 MFMAs per wave ----
    h8 af[3], bf[2];
#pragma unroll
    for (int mi = 0; mi < 3; ++mi)
      af[mi] = *(const h8*)&stage[(16 * mi + fr) * 32 + fq * 8];
#pragma unroll
    for (int ni = 0; ni < 2; ++ni)
      bf[ni] = *(const h8*)&stage[1536 + (w * 32 + 16 * ni + fr) * 32 + fq * 8];
#pragma unroll
    for (int mi = 0; mi < 3; ++mi)
#pragma unroll
      for (int ni = 0; ni < 2; ++ni)
        acc[mi][ni] = __builtin_amdgcn_mfma_f32_16x16x32_f16(
            af[mi], bf[ni], acc[mi][ni], 0, 0, 0);
    __syncthreads();
  }

  // ---- spill S tile to LDS: C/D layout col=lane&15, row=(lane>>4)*4+j ----
#pragma unroll
  for (int mi = 0; mi < 3; ++mi)
#pragma unroll
    for (int ni = 0; ni < 2; ++ni)
#pragma unroll
      for (int j = 0; j < 4; ++j)
        S[16 * mi + fq * 4 + j][w * 32 + 16 * ni + fr] = acc[mi][ni][j];
  __syncthreads();

  // ---- fused epilogue: waves {0,1}->t0, {2,3}->t1; each wave = 64 cols ----
  int col = tid & 63;
  int rg = (tid >> 6) & 1;   // row group (even/odd k)
  int th = tid >> 7;         // which caption of the pair
  int t = bx * 2 + th;
  int Ki = img_lens[iblk];
  int Lt = cap_lens[t];
  bool cvalid = col < Lt;

  // pass 1: block max over valid entries (shared by both softmax axes)
  float m = -1e30f;
  for (int k = rg; k < KIMG; k += 2)
    if (k < Ki && cvalid) m = fmaxf(m, S[k][th * 64 + col]);
  m = wave_red_max(m);
  if (lane == 0) mred[th][rg] = m;
  __syncthreads();
  float M = fmaxf(mred[th][0], mred[th][1]);

  // pass 2: e = exp((s-M)/lambda) for valid else 0; row + col reductions
  float ce = 0.f, ces = 0.f, vacc = 0.f;
  for (int k = rg; k < KIMG; k += 2) {
    float s = S[k][th * 64 + col];
    bool valid = (k < Ki) && cvalid;
    float e = valid ? __expf((s - M) * 20.0f) : 0.f;  // 1/LAMB = 20
    float es = e * s;
    ce += e;
    ces += es;
    float re = wave_red_sum(e);
    float res = wave_red_sum(es);
    if (k < Ki) vacc += res / re;   // v2t[k] summed over valid rows
  }
  colred[0][th][rg][col] = ce;
  colred[1][th][rg][col] = ces;
  if (lane == 0) vred[th][rg] = vacc;
  __syncthreads();

  if (rg == 0) {
    float tce = colred[0][th][0][col] + colred[0][th][1][col];
    float tces = colred[1][th][0][col] + colred[1][th][1][col];
    float tv = cvalid ? tces / tce : 0.f;   // t2v[l] for valid cols
    float t2v_total = wave_red_sum(tv);
    if (lane == 0) {
      float v2t_total = vred[th][0] + vred[th][1];
      out[(size_t)iblk * BT + t] =
          0.5f * (v2t_total / (float)Ki + t2v_total / (float)Lt);
    }
  }
}

extern "C" void kernel_launch(void* const* d_in, const int* in_sizes, int n_in,
                              void* d_out, int out_size, void* d_ws, size_t ws_size,
                              hipStream_t stream) {
  // setup_inputs order: img_cls, imgs, cap_cls, caps, img_lens, cap_lens
  const float* imgs = (const float*)d_in[1];
  const float* caps = (const float*)d_in[3];
  const int* img_lens = (const int*)d_in[4];
  const int* cap_lens = (const int*)d_in[5];
  float* out = (float*)d_out;

  _Float16* Ah = (_Float16*)d_ws;                    // [BI*MP][DD] = 12.6 MB
  _Float16* Bh = Ah + (size_t)BI * MP * DD;          // [BT*LCAP][DD] = 16.8 MB

  norm_kernel<<<BI * MP + BT * LCAP, 256, 0, stream>>>(imgs, caps, Ah, Bh);
  sims_kernel<<<dim3(BT / 2, BI), 256, 0, stream>>>(Ah, Bh, img_lens, cap_lens, out);
}

// Round 2
// 184.337 us; speedup vs baseline: 1.4752x; 1.4752x over previous
//
#include <hip/hip_runtime.h>
#include <stdint.h>

#define BI 128
#define BT 128
#define KIMG 36
#define LCAP 64
#define DD 1024
#define MP 48   // imgs K padded to 3x16 for MFMA alignment

typedef _Float16 h4 __attribute__((ext_vector_type(4)));
typedef _Float16 h8 __attribute__((ext_vector_type(8)));
typedef float f4 __attribute__((ext_vector_type(4)));

__device__ __forceinline__ float wave_red_sum(float v) {
#pragma unroll
  for (int o = 1; o < 64; o <<= 1) v += __shfl_xor(v, o, 64);
  return v;
}
__device__ __forceinline__ float wave_red_max(float v) {
#pragma unroll
  for (int o = 1; o < 64; o <<= 1) v = fmaxf(v, __shfl_xor(v, o, 64));
  return v;
}

// ---------------------------------------------------------------------------
// Kernel 1: add EPS, L2-normalize rows over D=1024, cast to fp16.
// imgs rows are written into a padded [BI][MP=48][DD] layout (rows 36..47 = 0).
// ---------------------------------------------------------------------------
__global__ __launch_bounds__(256) void norm_kernel(
    const float* __restrict__ imgs, const float* __restrict__ caps,
    _Float16* __restrict__ Ah, _Float16* __restrict__ Bh) {
  int row = blockIdx.x;
  int tid = threadIdx.x;
  const float* src;
  _Float16* dst;
  if (row < BI * MP) {
    int i = row / MP, k = row - i * MP;
    dst = Ah + (size_t)row * DD;
    if (k >= KIMG) {           // zero padding rows (block-uniform branch)
      h4 z = {};
      ((h4*)dst)[tid] = z;
      return;
    }
    src = imgs + ((size_t)i * KIMG + k) * DD;
  } else {
    int r = row - BI * MP;
    dst = Bh + (size_t)r * DD;
    src = caps + (size_t)r * DD;
  }
  float4 x = ((const float4*)src)[tid];
  x.x += 1e-6f; x.y += 1e-6f; x.z += 1e-6f; x.w += 1e-6f;
  float ss = x.x * x.x + x.y * x.y + x.z * x.z + x.w * x.w;
  ss = wave_red_sum(ss);
  __shared__ float red[4];
  int lane = tid & 63, w = tid >> 6;
  if (lane == 0) red[w] = ss;
  __syncthreads();
  float scale = rsqrtf(red[0] + red[1] + red[2] + red[3]);
  h4 o;
  o[0] = (_Float16)(x.x * scale);
  o[1] = (_Float16)(x.y * scale);
  o[2] = (_Float16)(x.z * scale);
  o[3] = (_Float16)(x.w * scale);
  ((h4*)dst)[tid] = o;
}

// ---------------------------------------------------------------------------
// Kernel 2: one image x 4 captions per block (48x256 tile), wave w = caption w.
// Swizzled LDS (involution s ^= (s>>3)&7 on 16B slots, per-region) staged via
// linear global_load_lds with pre-swizzled global source. Epilogue is fully
// register-resident: per-wave max + exp + row/col shuffle reductions.
// ---------------------------------------------------------------------------
__global__ __launch_bounds__(256, 4) void sims_kernel(
    const _Float16* __restrict__ Ah, const _Float16* __restrict__ Bh,
    const int* __restrict__ img_lens, const int* __restrict__ cap_lens,
    float* __restrict__ out) {
  // A region: 48 rows x 32 halves = 192 slots (3 KB) at byte 0
  // B region: 256 rows x 32 halves = 1024 slots (16 KB) at byte 3072
  __shared__ _Float16 stage[9728] __attribute__((aligned(16)));

  int tid = threadIdx.x;
  int lane = tid & 63;
  int w = tid >> 6;       // wave = caption within quad
  int bx = blockIdx.x;    // caption quad 0..31
  int iblk = blockIdx.y;  // image 0..127

  int fr = lane & 15;     // fragment row (M or N index)
  int fq = lane >> 4;     // k-segment 0..3

  const size_t arow0 = (size_t)iblk * MP;
  const size_t brow0 = (size_t)bx * 256;

  // ---- precompute swizzled fragment byte offsets (k-invariant) ----
  int aoff[3], boff[4];
#pragma unroll
  for (int mi = 0; mi < 3; ++mi) {
    int s = (16 * mi + fr) * 4 + fq;
    int sw = s ^ ((s >> 3) & 7);
    aoff[mi] = sw * 16;
  }
#pragma unroll
  for (int ni = 0; ni < 4; ++ni) {
    int s = (64 * w + 16 * ni + fr) * 4 + fq;
    int sw = s ^ ((s >> 3) & 7);
    boff[ni] = 3072 + sw * 16;
  }

  // ---- precompute staging global pointers (pre-swizzled source) ----
  // 19 chunks of 64 slots; wave w takes chunks w, w+4, ..., chunks 0..2 = A.
  const _Float16* gp[5];
  int ldsb[5];
#pragma unroll
  for (int it = 0; it < 5; ++it) {
    int c = w + 4 * it;
    if (c < 19) {
      int s = c * 64 + lane;
      bool isA = c < 3;
      int srel = isA ? s : s - 192;
      int sw = srel ^ ((srel >> 3) & 7);
      int row = sw >> 2, fqg = sw & 3;
      gp[it] = isA ? Ah + (arow0 + row) * DD + fqg * 8
                   : Bh + (brow0 + row) * DD + fqg * 8;
      ldsb[it] = c * 1024;
    }
  }

  f4 acc[3][4] = {};

  for (int k0 = 0; k0 < DD; k0 += 32) {
#pragma unroll
    for (int it = 0; it < 5; ++it) {
      if (w + 4 * it < 19) {
        __builtin_amdgcn_global_load_lds(
            (const __attribute__((address_space(1))) void*)(gp[it] + k0),
            (__attribute__((address_space(3))) void*)((char*)stage + ldsb[it]),
            16, 0, 0);
      }
    }
    __syncthreads();
    h8 af[3], bf[4];
#pragma unroll
    for (int mi = 0; mi < 3; ++mi)
      af[mi] = *(const h8*)((const char*)stage + aoff[mi]);
#pragma unroll
    for (int ni = 0; ni < 4; ++ni)
      bf[ni] = *(const h8*)((const char*)stage + boff[ni]);
#pragma unroll
    for (int mi = 0; mi < 3; ++mi)
#pragma unroll
      for (int ni = 0; ni < 4; ++ni)
        acc[mi][ni] = __builtin_amdgcn_mfma_f32_16x16x32_f16(
            af[mi], bf[ni], acc[mi][ni], 0, 0, 0);
    __syncthreads();
  }

  // ---- register epilogue: C/D layout col=16*ni+fr, row=16*mi+4*fq+j ----
  int Ki = img_lens[iblk];
  int t = bx * 4 + w;
  int Lt = cap_lens[t];

  float m = -1e30f;
#pragma unroll
  for (int mi = 0; mi < 3; ++mi)
#pragma unroll
    for (int ni = 0; ni < 4; ++ni)
#pragma unroll
      for (int j = 0; j < 4; ++j) {
        bool valid = (16 * mi + 4 * fq + j < Ki) && (16 * ni + fr < Lt);
        if (valid) m = fmaxf(m, acc[mi][ni][j]);
      }
  m = wave_red_max(m);

  float rowe[3][4] = {}, rowes[3][4] = {}, cole[4] = {}, coles[4] = {};
#pragma unroll
  for (int mi = 0; mi < 3; ++mi)
#pragma unroll
    for (int ni = 0; ni < 4; ++ni)
#pragma unroll
      for (int j = 0; j < 4; ++j) {
        float s = acc[mi][ni][j];
        bool valid = (16 * mi + 4 * fq + j < Ki) && (16 * ni + fr < Lt);
        float e = valid ? __expf((s - m) * 20.0f) : 0.f;  // 1/LAMB = 20
        float es = e * s;
        rowe[mi][j] += e;
        rowes[mi][j] += es;
        cole[ni] += e;
        coles[ni] += es;
      }

  // v2t: per row r=16*mi+4*fq+j, reduce over cols (fr lanes), then sum rows
  float part = 0.f;
#pragma unroll
  for (int mi = 0; mi < 3; ++mi)
#pragma unroll
    for (int j = 0; j < 4; ++j) {
      float Re = rowe[mi][j], Res = rowes[mi][j];
#pragma unroll
      for (int o = 1; o < 16; o <<= 1) {
        Re += __shfl_xor(Re, o, 64);
        Res += __shfl_xor(Res, o, 64);
      }
      int row = 16 * mi + 4 * fq + j;
      if (fr == 0 && row < Ki) part += (Res / Re) * (0.5f / (float)Ki);
    }
  // t2v: per col l=16*ni+fr, reduce over rows (fq lanes), then sum cols
#pragma unroll
  for (int ni = 0; ni < 4; ++ni) {
    float Ce = cole[ni], Ces = coles[ni];
#pragma unroll
    for (int o = 16; o < 64; o <<= 1) {
      Ce += __shfl_xor(Ce, o, 64);
      Ces += __shfl_xor(Ces, o, 64);
    }
    int l = 16 * ni + fr;
    if (fq == 0 && l < Lt) part += (Ces / Ce) * (0.5f / (float)Lt);
  }
  float sim = wave_red_sum(part);
  if (lane == 0) out[(size_t)iblk * BT + t] = sim;
}

extern "C" void kernel_launch(void* const* d_in, const int* in_sizes, int n_in,
                              void* d_out, int out_size, void* d_ws, size_t ws_size,
                              hipStream_t stream) {
  // setup_inputs order: img_cls, imgs, cap_cls, caps, img_lens, cap_lens
  const float* imgs = (const float*)d_in[1];
  const float* caps = (const float*)d_in[3];
  const int* img_lens = (const int*)d_in[4];
  const int* cap_lens = (const int*)d_in[5];
  float* out = (float*)d_out;

  _Float16* Ah = (_Float16*)d_ws;                    // [BI*MP][DD] = 12.6 MB
  _Float16* Bh = Ah + (size_t)BI * MP * DD;          // [BT*LCAP][DD] = 16.8 MB

  norm_kernel<<<BI * MP + BT * LCAP, 256, 0, stream>>>(imgs, caps, Ah, Bh);
  sims_kernel<<<dim3(BT / 4, BI), 256, 0, stream>>>(Ah, Bh, img_lens, cap_lens, out);
}

// Round 3
// 150.907 us; speedup vs baseline: 1.8020x; 1.2215x over previous
//
#include <hip/hip_runtime.h>
#include <stdint.h>

#define BI 128
#define BT 128
#define KIMG 36
#define LCAP 64
#define DD 1024
#define MP 48        // imgs K padded to 3x16 for MFMA alignment
#define MB 96        // rows per block = 2 padded images
#define NB 256       // cols per block = 4 captions
#define ASLOTS 384   // A region 16B-slots (96 rows x 64 B)
#define ABYTES 6144
#define STG_BYTES 22528  // one staging buffer (A 6KB + B 16KB)

typedef _Float16 h4 __attribute__((ext_vector_type(4)));
typedef _Float16 h8 __attribute__((ext_vector_type(8)));
typedef float f4 __attribute__((ext_vector_type(4)));

__device__ __forceinline__ float wave_red_sum(float v) {
#pragma unroll
  for (int o = 1; o < 64; o <<= 1) v += __shfl_xor(v, o, 64);
  return v;
}
__device__ __forceinline__ float wave_red_max(float v) {
#pragma unroll
  for (int o = 1; o < 64; o <<= 1) v = fmaxf(v, __shfl_xor(v, o, 64));
  return v;
}

// ---------------------------------------------------------------------------
// Kernel 1: add EPS, L2-normalize rows over D=1024, cast to fp16.
// imgs rows go to padded [BI][MP=48][DD] layout (rows 36..47 = 0).
// ---------------------------------------------------------------------------
__global__ __launch_bounds__(256) void norm_kernel(
    const float* __restrict__ imgs, const float* __restrict__ caps,
    _Float16* __restrict__ Ah, _Float16* __restrict__ Bh) {
  int row = blockIdx.x;
  int tid = threadIdx.x;
  const float* src;
  _Float16* dst;
  if (row < BI * MP) {
    int i = row / MP, k = row - i * MP;
    dst = Ah + (size_t)row * DD;
    if (k >= KIMG) {           // zero padding rows (block-uniform branch)
      h4 z = {};
      ((h4*)dst)[tid] = z;
      return;
    }
    src = imgs + ((size_t)i * KIMG + k) * DD;
  } else {
    int r = row - BI * MP;
    dst = Bh + (size_t)r * DD;
    src = caps + (size_t)r * DD;
  }
  float4 x = ((const float4*)src)[tid];
  x.x += 1e-6f; x.y += 1e-6f; x.z += 1e-6f; x.w += 1e-6f;
  float ss = x.x * x.x + x.y * x.y + x.z * x.z + x.w * x.w;
  ss = wave_red_sum(ss);
  __shared__ float red[4];
  int lane = tid & 63, w = tid >> 6;
  if (lane == 0) red[w] = ss;
  __syncthreads();
  float scale = rsqrtf(red[0] + red[1] + red[2] + red[3]);
  h4 o;
  o[0] = (_Float16)(x.x * scale);
  o[1] = (_Float16)(x.y * scale);
  o[2] = (_Float16)(x.z * scale);
  o[3] = (_Float16)(x.w * scale);
  ((h4*)dst)[tid] = o;
}

// ---------------------------------------------------------------------------
// Kernel 2: 2 images x 4 captions per block (96x256 tile), wave w = caption w.
// Double-buffered swizzled LDS, 2-phase pipeline (STAGE next || compute cur,
// single barrier per k-step). Register-resident masked-softmax epilogue.
// Swizzle: 16B-slot involution s ^= (s>>3)&7 per region; LDS dest linear,
// global source pre-swizzled (rule 21), frag reads apply same involution.
// ---------------------------------------------------------------------------
__global__ __launch_bounds__(256, 3) void sims_kernel(
    const _Float16* __restrict__ Ah, const _Float16* __restrict__ Bh,
    const int* __restrict__ img_lens, const int* __restrict__ cap_lens,
    float* __restrict__ out) {
  __shared__ char stage[2 * STG_BYTES] __attribute__((aligned(16)));

  int tid = threadIdx.x;
  int lane = tid & 63;
  int w = tid >> 6;       // wave = caption within quad
  int bx = blockIdx.x;    // caption quad 0..31
  int by = blockIdx.y;    // image pair 0..63
  int fr = lane & 15;
  int fq = lane >> 4;

  const size_t arow0 = (size_t)by * MB;    // into padded A rows
  const size_t brow0 = (size_t)bx * NB;

  // ---- staging plan: wave w owns contiguous chunks; one base ptr + stride --
  // chunks: w0:0-5 (A), w1:6-11, w2:12-16, w3:17-21 (B). 64 slots/chunk.
  int c0 = 6 * w - ((w >> 1) & (w & 1));   // {0,6,12,17}
  int nch = (w < 2) ? 6 : 5;
  int s0 = c0 * 64 + lane;
  bool isA = (w == 0);
  int srel = isA ? s0 : s0 - ASLOTS;
  int sw0 = srel ^ ((srel >> 3) & 7);
  const _Float16* gp0 =
      (isA ? Ah + arow0 * DD : Bh + brow0 * DD) + (size_t)(sw0 >> 2) * DD + (sw0 & 3) * 8;
  const int lds0 = c0 * 1024 + lane * 16;

  // ---- swizzled fragment byte offsets (k-invariant) ----
  int aoff[6], boff[4];
#pragma unroll
  for (int mi = 0; mi < 6; ++mi) {
    int s = (16 * mi + fr) * 4 + fq;
    aoff[mi] = (s ^ ((s >> 3) & 7)) * 16;
  }
#pragma unroll
  for (int ni = 0; ni < 4; ++ni) {
    int s = (64 * w + 16 * ni + fr) * 4 + fq;
    boff[ni] = ABYTES + (s ^ ((s >> 3) & 7)) * 16;
  }

  auto STAGE = [&](int buf, int k0) {
#pragma unroll
    for (int it = 0; it < 6; ++it) {
      if (it < nch) {
        __builtin_amdgcn_global_load_lds(
            (const __attribute__((address_space(1))) void*)(gp0 + (size_t)it * 16 * DD + k0),
            (__attribute__((address_space(3))) void*)(stage + buf * STG_BYTES + lds0 + it * 1024),
            16, 0, 0);
      }
    }
  };

  f4 acc[6][4] = {};

  STAGE(0, 0);
  __syncthreads();

  for (int t = 0; t < 32; ++t) {
    const char* rb = stage + (t & 1) * STG_BYTES;
    if (t < 31) STAGE((t + 1) & 1, 32 * (t + 1));
    h8 af[6], bf[4];
#pragma unroll
    for (int mi = 0; mi < 6; ++mi)
      af[mi] = *(const h8*)(rb + aoff[mi]);
#pragma unroll
    for (int ni = 0; ni < 4; ++ni)
      bf[ni] = *(const h8*)(rb + boff[ni]);
#pragma unroll
    for (int mi = 0; mi < 6; ++mi)
#pragma unroll
      for (int ni = 0; ni < 4; ++ni)
        acc[mi][ni] = __builtin_amdgcn_mfma_f32_16x16x32_f16(
            af[mi], bf[ni], acc[mi][ni], 0, 0, 0);
    __syncthreads();
  }

  // ---- register epilogue: C/D layout col=16*ni+fr, row=16*mi+4*fq+j ----
  int t = bx * 4 + w;
  int Lt = cap_lens[t];

#pragma unroll
  for (int img = 0; img < 2; ++img) {
    int Ki = img_lens[2 * by + img];

    float m = -1e30f;
#pragma unroll
    for (int mi = 0; mi < 3; ++mi)
#pragma unroll
      for (int ni = 0; ni < 4; ++ni)
#pragma unroll
        for (int j = 0; j < 4; ++j) {
          bool valid = (16 * mi + 4 * fq + j < Ki) && (16 * ni + fr < Lt);
          if (valid) m = fmaxf(m, acc[3 * img + mi][ni][j]);
        }
    m = wave_red_max(m);

    float rowe[3][4] = {}, rowes[3][4] = {}, cole[4] = {}, coles[4] = {};
#pragma unroll
    for (int mi = 0; mi < 3; ++mi)
#pragma unroll
      for (int ni = 0; ni < 4; ++ni)
#pragma unroll
        for (int j = 0; j < 4; ++j) {
          float s = acc[3 * img + mi][ni][j];
          bool valid = (16 * mi + 4 * fq + j < Ki) && (16 * ni + fr < Lt);
          float e = valid ? __expf((s - m) * 20.0f) : 0.f;  // 1/LAMB = 20
          float es = e * s;
          rowe[mi][j] += e;
          rowes[mi][j] += es;
          cole[ni] += e;
          coles[ni] += es;
        }

    // v2t: per row, reduce over cols (fr lanes), then accumulate rows
    float part = 0.f;
#pragma unroll
    for (int mi = 0; mi < 3; ++mi)
#pragma unroll
      for (int j = 0; j < 4; ++j) {
        float Re = rowe[mi][j], Res = rowes[mi][j];
#pragma unroll
        for (int o = 1; o < 16; o <<= 1) {
          Re += __shfl_xor(Re, o, 64);
          Res += __shfl_xor(Res, o, 64);
        }
        int row = 16 * mi + 4 * fq + j;
        if (fr == 0 && row < Ki) part += (Res / Re) * (0.5f / (float)Ki);
      }
    // t2v: per col, reduce over rows (fq lanes), then accumulate cols
#pragma unroll
    for (int ni = 0; ni < 4; ++ni) {
      float Ce = cole[ni], Ces = coles[ni];
#pragma unroll
      for (int o = 16; o < 64; o <<= 1) {
        Ce += __shfl_xor(Ce, o, 64);
        Ces += __shfl_xor(Ces, o, 64);
      }
      int l = 16 * ni + fr;
      if (fq == 0 && l < Lt) part += (Ces / Ce) * (0.5f / (float)Lt);
    }
    float sim = wave_red_sum(part);
    if (lane == 0) out[(size_t)(2 * by + img) * BT + t] = sim;
  }
}

extern "C" void kernel_launch(void* const* d_in, const int* in_sizes, int n_in,
                              void* d_out, int out_size, void* d_ws, size_t ws_size,
                              hipStream_t stream) {
  // setup_inputs order: img_cls, imgs, cap_cls, caps, img_lens, cap_lens
  const float* imgs = (const float*)d_in[1];
  const float* caps = (const float*)d_in[3];
  const int* img_lens = (const int*)d_in[4];
  const int* cap_lens = (const int*)d_in[5];
  float* out = (float*)d_out;

  _Float16* Ah = (_Float16*)d_ws;                    // [BI*MP][DD] = 12.6 MB
  _Float16* Bh = Ah + (size_t)BI * MP * DD;          // [BT*LCAP][DD] = 16.8 MB

  norm_kernel<<<BI * MP + BT * LCAP, 256, 0, stream>>>(imgs, caps, Ah, Bh);
  sims_kernel<<<dim3(BT / 4, BI / 2), 256, 0, stream>>>(Ah, Bh, img_lens, cap_lens, out);
}